// Round 2
// baseline (167.481 us; speedup 1.0000x reference)
//
#include <hip/hip_runtime.h>
#include <math.h>

// CIRNet fully-fused, register-direct: T=1048576 rows x 18 feats -> r_predicts/regs/dts.
// 256 blocks x 1024 threads (grid == #CUs -> co-resident for the device barrier).
// Each thread owns 4 consecutive rows (288B, 16B-aligned): reads them as 18 float4
// directly to registers (contiguous wave footprint, high MLP, NO LDS staging -> no
// vmcnt(0)-at-barrier serialization that sank the chunked version), computes the 4
// (d,c) coefficients + regs/dts in-register, then the validated tail:
// Newton-linearized affine map -> block scan -> device-scope spin barrier ->
// shuffle-based global scan over 256 block aggregates -> replay + store.
// FP math order identical to the validated kernel (same fma chains, same seed).
#define NSTEPS   1048575
#define FEAT     18
#define NB       256                 // blocks (== CUs -> co-resident)
#define NT       1024                // threads per block
#define NTHREADS (NB * NT)           // 262144 threads x 4 rows = 1048576 rows

// one step + derivative-product update (identical math to validated kernel)
#define GSTEP(dd, cc) { \
    float a   = fmaf(-k, (dd), 1.f); \
    float b   = kth * (dd); \
    float ar  = fabsf(r); \
    float sq  = sqrtf(ar); \
    float inv = (ar > 1e-30f) ? rsqrtf(ar) : 0.f; \
    float g   = fmaf(0.5f * (cc), copysignf(inv, r), a); \
    r = fmaf((cc), sq, fmaf(a, r, b)); \
    P *= g; }

#define FSTEP(dd, cc) { \
    float a = fmaf(-k, (dd), 1.f); \
    float b = kth * (dd); \
    rr = fmaf((cc), sqrtf(fabsf(rr)), fmaf(a, rr, b)); }

// sig/eps/c for one row from 16 register features (same fma order as validated kernel)
#define ROWCOEF(S0,S1,S2,S3,S4,S5,S6,S7, E0,E1,E2,E3,E4,E5,E6,E7, dv, sigv, cvv) { \
    float sig_ = sb0; \
    sig_ = fmaf((S0), sw0, sig_); sig_ = fmaf((S1), sw1, sig_); \
    sig_ = fmaf((S2), sw2, sig_); sig_ = fmaf((S3), sw3, sig_); \
    sig_ = fmaf((S4), sw4, sig_); sig_ = fmaf((S5), sw5, sig_); \
    sig_ = fmaf((S6), sw6, sig_); sig_ = fmaf((S7), sw7, sig_); \
    float ep_ = 0.f; \
    ep_ = fmaf((E0), ew0, ep_); ep_ = fmaf((E1), ew1, ep_); \
    ep_ = fmaf((E2), ew2, ep_); ep_ = fmaf((E3), ew3, ep_); \
    ep_ = fmaf((E4), ew4, ep_); ep_ = fmaf((E5), ew5, ep_); \
    ep_ = fmaf((E6), ew6, ep_); ep_ = fmaf((E7), ew7, ep_); \
    (sigv) = sig_; (cvv) = sig_ * ep_ * sqrtf(fabsf(dv)); }

__device__ __forceinline__ void wave_scan_affine(float& A, float& B, int lane) {
#pragma unroll
    for (int d = 1; d < 64; d <<= 1) {
        float pA = __shfl_up(A, d, 64);
        float pB = __shfl_up(B, d, 64);
        if (lane >= d) { B = fmaf(A, pB, B); A *= pA; }
    }
}

__global__ void __launch_bounds__(NT) cir_fused(
    const float* __restrict__ trace,
    const float* __restrict__ sW, const float* __restrict__ sb,
    const float* __restrict__ eW, const float* __restrict__ kp,
    const float* __restrict__ thp,
    float* __restrict__ out,
    float* __restrict__ gA, float* __restrict__ gB,
    unsigned int* __restrict__ cnt)
{
    __shared__ float wAs[16], wBs[16];
    __shared__ float sgA[NB], sgB[NB];

    const int tid = threadIdx.x, lane = tid & 63, wid = tid >> 6, bid = blockIdx.x;
    const long c = (long)bid * NT + tid;          // thread's chunk index (4 rows)

    // ---- direct register load of own 4 rows: 18 x float4, contiguous & aligned ----
    const float4* __restrict__ src = (const float4*)trace + c * 18;
    float4 v0  = src[0],  v1  = src[1],  v2  = src[2],  v3  = src[3],  v4  = src[4];
    float4 v5  = src[5],  v6  = src[6],  v7  = src[7],  v8  = src[8];
    float4 v9  = src[9],  v10 = src[10], v11 = src[11], v12 = src[12], v13 = src[13];
    float4 v14 = src[14], v15 = src[15], v16 = src[16], v17 = src[17];

    const float k = kp[0], th = thp[0], kth = k * th, tkth2 = 2.f * kth;
    const float sb0 = sb[0];
    const float sw0 = sW[0], sw1 = sW[1], sw2 = sW[2], sw3 = sW[3];
    const float sw4 = sW[4], sw5 = sW[5], sw6 = sW[6], sw7 = sW[7];
    const float ew0 = eW[0], ew1 = eW[1], ew2 = eW[2], ew3 = eW[3];
    const float ew4 = eW[4], ew5 = eW[5], ew6 = eW[6], ew7 = eW[7];
    const float t0g = trace[0], r0v = trace[1];

    // t of next thread's first row (row 4c+4): shuffle; lane 63 loads (1 txn/wave)
    float tnext = __shfl_down(v0.x, 1, 64);
    if (lane == 63)
        tnext = (c + 1 < (long)NTHREADS) ? trace[(c * 4 + 4) * FEAT] : 0.f;

    // ---- coefficients for the 4 owned steps (row j -> floats 18j..18j+17) ----
    float d0 = v4.z  - v0.x;     // t1 - t0   (t1 = f18 = v4.z)
    float d1 = v9.x  - v4.z;     // t2 - t1   (t2 = f36 = v9.x)
    float d2 = v13.z - v9.x;     // t3 - t2   (t3 = f54 = v13.z)
    float d3 = tnext - v13.z;    // t4 - t3
    float sig0, c0v, sig1, c1v, sig2, c2v, sig3, c3v;
    ROWCOEF(v0.z,v0.w,v1.x,v1.y,v1.z,v1.w,v2.x,v2.y,
            v2.z,v2.w,v3.x,v3.y,v3.z,v3.w,v4.x,v4.y, d0, sig0, c0v)
    ROWCOEF(v5.x,v5.y,v5.z,v5.w,v6.x,v6.y,v6.z,v6.w,
            v7.x,v7.y,v7.z,v7.w,v8.x,v8.y,v8.z,v8.w, d1, sig1, c1v)
    ROWCOEF(v9.z,v9.w,v10.x,v10.y,v10.z,v10.w,v11.x,v11.y,
            v11.z,v11.w,v12.x,v12.y,v12.z,v12.w,v13.x,v13.y, d2, sig2, c2v)
    ROWCOEF(v14.x,v14.y,v14.z,v14.w,v15.x,v15.y,v15.z,v15.w,
            v16.x,v16.y,v16.z,v16.w,v17.x,v17.y,v17.z,v17.w, d3, sig3, c3v)

    const long n0 = c * 4;
    if (n0 + 4 > NSTEPS) { d3 = 0.f; c3v = 0.f; }     // step NSTEPS is pad (identity)

    // regs/dts stores (4B lanes at 16B stride: 4 lanes/line, fully-written lines)
    out[NSTEPS + n0 + 0] = fmaf(-sig0, sig0, tkth2);
    out[NSTEPS + n0 + 1] = fmaf(-sig1, sig1, tkth2);
    out[NSTEPS + n0 + 2] = fmaf(-sig2, sig2, tkth2);
    out[2L * NSTEPS + n0 + 0] = d0;
    out[2L * NSTEPS + n0 + 1] = d1;
    out[2L * NSTEPS + n0 + 2] = d2;
    if (n0 + 4 <= NSTEPS) {
        out[NSTEPS + n0 + 3] = fmaf(-sig3, sig3, tkth2);
        out[2L * NSTEPS + n0 + 3] = d3;
    }

    const float4 q0 = make_float4(d0, c0v, d1, c1v);
    const float4 q1 = make_float4(d2, c2v, d3, c3v);

    // ---- tail: identical math to validated fused_pass ----
    float s = th + (r0v - th) * __expf(-k * (v0.x - t0g));   // closed-form ODE seed
    float r = s, P = 1.f;
    GSTEP(q0.x, q0.y)
    GSTEP(q0.z, q0.w)
    GSTEP(q1.x, q1.y)
    GSTEP(q1.z, q1.w)
    float A = P, Bv = fmaf(-P, s, r);

    float iA = A, iB = Bv;
    wave_scan_affine(iA, iB, lane);
    if (lane == 63) { wAs[wid] = iA; wBs[wid] = iB; }
    __syncthreads();
    if (wid == 0) {
        float aA = (lane < 16) ? wAs[lane] : 1.f;
        float aB = (lane < 16) ? wBs[lane] : 0.f;
        wave_scan_affine(aA, aB, lane);
        if (lane < 16) { wAs[lane] = aA; wBs[lane] = aB; }
    }
    __syncthreads();
    float weA = 1.f, weB = 0.f;
    if (wid > 0) { weA = wAs[wid - 1]; weB = wBs[wid - 1]; }
    float eA = __shfl_up(iA, 1, 64), eB = __shfl_up(iB, 1, 64);
    if (lane == 0) { eA = 1.f; eB = 0.f; }
    float Ate = eA * weA;                 // thread-exclusive prefix within block
    float Bte = fmaf(eA, weB, eB);

    // publish block aggregate + device-scope spin barrier (tid 0 only, others sync)
    if (tid == 0) {
        __hip_atomic_store(&gA[bid], wAs[15], __ATOMIC_RELAXED, __HIP_MEMORY_SCOPE_AGENT);
        __hip_atomic_store(&gB[bid], wBs[15], __ATOMIC_RELAXED, __HIP_MEMORY_SCOPE_AGENT);
        __hip_atomic_fetch_add(cnt, 1u, __ATOMIC_ACQ_REL, __HIP_MEMORY_SCOPE_AGENT);
        while (__hip_atomic_load(cnt, __ATOMIC_ACQUIRE, __HIP_MEMORY_SCOPE_AGENT) < NB)
            __builtin_amdgcn_s_sleep(1);
    }
    __syncthreads();

    // shuffle-based scan of the 256 block aggregates (waves 0..3, 3 barriers total)
    float bAv = 1.f, bBv = 0.f;
    if (tid < NB) {
        bAv = __hip_atomic_load(&gA[tid], __ATOMIC_RELAXED, __HIP_MEMORY_SCOPE_AGENT);
        bBv = __hip_atomic_load(&gB[tid], __ATOMIC_RELAXED, __HIP_MEMORY_SCOPE_AGENT);
    }
    if (wid < NB / 64) {
        wave_scan_affine(bAv, bBv, lane);            // inclusive within wave
        if (lane == 63) { wAs[wid] = bAv; wBs[wid] = bBv; }  // wave aggregates (reuse)
    }
    __syncthreads();
    if (tid < NB) {
        float Pa = 1.f, Pb = 0.f;                    // prefix of earlier waves
        for (int w = 0; w < wid; ++w) { Pb = fmaf(wAs[w], Pb, wBs[w]); Pa *= wAs[w]; }
        sgA[tid] = bAv * Pa;                         // full inclusive for block tid
        sgB[tid] = fmaf(bAv, Pb, bBv);
    }
    __syncthreads();
    float beA = 1.f, beB = 0.f;
    if (bid > 0) { beA = sgA[bid - 1]; beB = sgB[bid - 1]; }

    // corrected start for this thread's 4 steps, replay, store
    float FA = Ate * beA;
    float FB = fmaf(Ate, beB, Bte);
    float rr = fmaf(FA, r0v, FB);
    float4 ov;
    FSTEP(q0.x, q0.y) ov.x = rr;
    FSTEP(q0.z, q0.w) ov.y = rr;
    FSTEP(q1.x, q1.y) ov.z = rr;
    FSTEP(q1.z, q1.w) ov.w = rr;
    long nb = 4 * c;
    if (nb + 4 <= NSTEPS) {
        *(float4*)(out + nb) = ov;
    } else {                        // last thread only (step NSTEPS is pad)
        out[nb + 0] = ov.x;
        out[nb + 1] = ov.y;
        out[nb + 2] = ov.z;
    }
}

extern "C" void kernel_launch(void* const* d_in, const int* in_sizes, int n_in,
                              void* d_out, int out_size, void* d_ws, size_t ws_size,
                              hipStream_t stream)
{
    const float* trace = (const float*)d_in[0];
    const float* sW    = (const float*)d_in[1];
    const float* sb    = (const float*)d_in[2];
    const float* eW    = (const float*)d_in[3];
    const float* kp    = (const float*)d_in[4];
    const float* thp   = (const float*)d_in[5];
    float* out = (float*)d_out;

    float*        gA  = (float*)d_ws;
    float*        gB  = gA + NB;
    unsigned int* cnt = (unsigned int*)(gB + NB);

    hipMemsetAsync(cnt, 0, sizeof(unsigned int), stream);   // graph-capture-legal memset
    cir_fused<<<NB, NT, 0, stream>>>(trace, sW, sb, eW, kp, thp, out, gA, gB, cnt);
}

// Round 3
// 151.467 us; speedup vs baseline: 1.1057x; 1.1057x over previous
//
#include <hip/hip_runtime.h>
#include <math.h>

// CIRNet fused, per-wave LDS transpose: T=1048576 rows x 18 feats -> r_predicts/regs/dts.
// 256 blocks x 1024 threads, 1 block/CU (157.8KB LDS) -> co-resident device barrier.
// Each thread owns 4 consecutive rows (one "quad" = 18 float4 = 288B). Direct reads are
// stride-288 (64 lines/instr, TA-bound: round-2 pathology); cross-wave LDS staging
// serializes on __syncthreads vmcnt(0) drain (round-1 pathology). Fix: each wave stages
// its own 64-quad region through a PRIVATE 9.5KB LDS buffer in two half-wave passes of
// coalesced global_load_lds dwordx4, synced only by wave-local s_waitcnt (no barriers).
// LDS layout pads quads to 19 float4 (odd stride -> <=4-way bank aliasing on
// ds_read_b128 extraction). Pad slots duplicate col-17 (in-bounds, ~5% extra fetch).
// Tail (Newton-linearized affine map -> block scan -> device-scope spin barrier ->
// shuffle global scan -> replay + store) is identical to the validated kernel.
#define NSTEPS   1048575
#define FEAT     18
#define NB       256                 // blocks (== CUs -> co-resident)
#define NT       1024                // threads per block
#define NWAVE    (NT / 64)           // 16
#define NTHREADS (NB * NT)           // 262144 quads x 4 rows = 1048576 rows
#define SLOTS    608                 // 19 * 32 float4 slots per half-wave pass
#define WBYTES   (SLOTS * 16)        // 9728 B per-wave stage buffer

#define GLDS16(g, l) \
    __builtin_amdgcn_global_load_lds((const __attribute__((address_space(1))) void*)(g), \
                                     (__attribute__((address_space(3))) void*)(l), 16, 0, 0)

#define WAIT_VM0()   asm volatile("s_waitcnt vmcnt(0)" ::: "memory")
#define WAIT_LGKM0() asm volatile("s_waitcnt lgkmcnt(0)" ::: "memory")

// one step + derivative-product update (identical math to validated kernel)
#define GSTEP(dd, cc) { \
    float a   = fmaf(-k, (dd), 1.f); \
    float b   = kth * (dd); \
    float ar  = fabsf(r); \
    float sq  = sqrtf(ar); \
    float inv = (ar > 1e-30f) ? rsqrtf(ar) : 0.f; \
    float g   = fmaf(0.5f * (cc), copysignf(inv, r), a); \
    r = fmaf((cc), sq, fmaf(a, r, b)); \
    P *= g; }

#define FSTEP(dd, cc) { \
    float a = fmaf(-k, (dd), 1.f); \
    float b = kth * (dd); \
    rr = fmaf((cc), sqrtf(fabsf(rr)), fmaf(a, rr, b)); }

// sig & eps dot-products, same fma order as validated kernel
#define DOTSE(S0,S1,S2,S3,S4,S5,S6,S7, E0,E1,E2,E3,E4,E5,E6,E7, sigv, epv) { \
    float sig_ = sb0; \
    sig_ = fmaf((S0), sw0, sig_); sig_ = fmaf((S1), sw1, sig_); \
    sig_ = fmaf((S2), sw2, sig_); sig_ = fmaf((S3), sw3, sig_); \
    sig_ = fmaf((S4), sw4, sig_); sig_ = fmaf((S5), sw5, sig_); \
    sig_ = fmaf((S6), sw6, sig_); sig_ = fmaf((S7), sw7, sig_); \
    float ep_ = 0.f; \
    ep_ = fmaf((E0), ew0, ep_); ep_ = fmaf((E1), ew1, ep_); \
    ep_ = fmaf((E2), ew2, ep_); ep_ = fmaf((E3), ew3, ep_); \
    ep_ = fmaf((E4), ew4, ep_); ep_ = fmaf((E5), ew5, ep_); \
    ep_ = fmaf((E6), ew6, ep_); ep_ = fmaf((E7), ew7, ep_); \
    (sigv) = sig_; (epv) = ep_; }

// read one padded quad (18 float4 at stride-19 slots) and reduce to 15 live scalars
#define EXTRACT_COMPUTE(JROW) { \
    const float4* sr = (const float4*)lw + 19 * (JROW); \
    float4 u0 = sr[0],  u1  = sr[1],  u2  = sr[2],  u3  = sr[3],  u4  = sr[4]; \
    float4 u5 = sr[5],  u6  = sr[6],  u7  = sr[7],  u8  = sr[8]; \
    float4 u9 = sr[9],  u10 = sr[10], u11 = sr[11], u12 = sr[12], u13 = sr[13]; \
    float4 u14 = sr[14], u15 = sr[15], u16 = sr[16], u17 = sr[17]; \
    tfirst = u0.x; t3 = u13.z; \
    d0 = u4.z  - u0.x;  d1 = u9.x - u4.z;  d2 = u13.z - u9.x; \
    float ep0, ep1, ep2; \
    DOTSE(u0.z,u0.w,u1.x,u1.y,u1.z,u1.w,u2.x,u2.y, \
          u2.z,u2.w,u3.x,u3.y,u3.z,u3.w,u4.x,u4.y, sig0, ep0) \
    DOTSE(u5.x,u5.y,u5.z,u5.w,u6.x,u6.y,u6.z,u6.w, \
          u7.x,u7.y,u7.z,u7.w,u8.x,u8.y,u8.z,u8.w, sig1, ep1) \
    DOTSE(u9.z,u9.w,u10.x,u10.y,u10.z,u10.w,u11.x,u11.y, \
          u11.z,u11.w,u12.x,u12.y,u12.z,u12.w,u13.x,u13.y, sig2, ep2) \
    DOTSE(u14.x,u14.y,u14.z,u14.w,u15.x,u15.y,u15.z,u15.w, \
          u16.x,u16.y,u16.z,u16.w,u17.x,u17.y,u17.z,u17.w, sig3, ep3) \
    c0v = sig0 * ep0 * sqrtf(fabsf(d0)); \
    c1v = sig1 * ep1 * sqrtf(fabsf(d1)); \
    c2v = sig2 * ep2 * sqrtf(fabsf(d2)); }

__device__ __forceinline__ void stage_pass(const float4* __restrict__ base4,
                                           char* lds_wave, int lane)
{
    int jr = lane / 19;                 // quad within pass
    int ic = lane - 19 * jr;            // padded col
#pragma unroll
    for (int i = 0; i < 10; ++i) {
        int col = (ic == 18) ? 17 : ic; // pad slot -> duplicate col 17 (in-bounds)
        const float4* src = base4 + (18 * jr + col);
        if (i < 9) {
            GLDS16(src, lds_wave + i * 1024);
        } else if (lane < 32) {         // partial tail: slots 576..607 (exec-masked)
            GLDS16(src, lds_wave + 9 * 1024);
        }
        jr += 3; ic += 7;               // advance s by 64 = 3*19 + 7
        if (ic >= 19) { ic -= 19; ++jr; }
    }
}

__device__ __forceinline__ void wave_scan_affine(float& A, float& B, int lane) {
#pragma unroll
    for (int d = 1; d < 64; d <<= 1) {
        float pA = __shfl_up(A, d, 64);
        float pB = __shfl_up(B, d, 64);
        if (lane >= d) { B = fmaf(A, pB, B); A *= pA; }
    }
}

__global__ void __launch_bounds__(NT) cir_fused(
    const float* __restrict__ trace,
    const float* __restrict__ sW, const float* __restrict__ sb,
    const float* __restrict__ eW, const float* __restrict__ kp,
    const float* __restrict__ thp,
    float* __restrict__ out,
    float* __restrict__ gA, float* __restrict__ gB,
    unsigned int* __restrict__ cnt)
{
    __shared__ __align__(16) char stage[NWAVE * WBYTES];    // 155648 B
    __shared__ float wAs[16], wBs[16];
    __shared__ float sgA[NB], sgB[NB];                      // +2176 B = 157824 B total

    const int tid = threadIdx.x, lane = tid & 63, wid = tid >> 6, bid = blockIdx.x;
    const long c = (long)bid * NT + tid;                    // thread's quad index
    char* lw = stage + wid * WBYTES;                        // per-wave private buffer
    const float4* t4 = (const float4*)trace;
    const long waveQuad = (long)bid * NT + (long)wid * 64;  // wave's first quad

    // ---- pass 0: quads [waveQuad, +32) for lanes 0..31 ----
    stage_pass(t4 + waveQuad * 18, lw, lane);

    // scalar params load under the DMA latency
    const float k = kp[0], th = thp[0], kth = k * th, tkth2 = 2.f * kth;
    const float sb0 = sb[0];
    const float sw0 = sW[0], sw1 = sW[1], sw2 = sW[2], sw3 = sW[3];
    const float sw4 = sW[4], sw5 = sW[5], sw6 = sW[6], sw7 = sW[7];
    const float ew0 = eW[0], ew1 = eW[1], ew2 = eW[2], ew3 = eW[3];
    const float ew4 = eW[4], ew5 = eW[5], ew6 = eW[6], ew7 = eW[7];
    const float t0g = trace[0], r0v = trace[1];

    float tfirst, t3, d0, d1, d2, c0v, c1v, c2v, sig0, sig1, sig2, sig3, ep3;

    WAIT_VM0();                         // pass-0 data in LDS (wave-local wait)
    if (lane < 32) EXTRACT_COMPUTE(lane)
    WAIT_LGKM0();                       // extraction reads done before overwrite

    // ---- pass 1: quads [waveQuad+32, +32) for lanes 32..63 ----
    stage_pass(t4 + (waveQuad + 32) * 18, lw, lane);
    WAIT_VM0();
    if (lane >= 32) EXTRACT_COMPUTE(lane - 32)

    // t of next thread's first row: cross-half shuffle; lane 63 loads (1 txn/wave)
    float tnext = __shfl_down(tfirst, 1, 64);
    if (lane == 63)
        tnext = (c + 1 < (long)NTHREADS) ? trace[(c * 4 + 4) * FEAT] : 0.f;
    float d3 = tnext - t3;
    const long n0 = c * 4;
    float c3v = sig3 * ep3 * sqrtf(fabsf(d3));
    if (n0 + 4 > NSTEPS) { d3 = 0.f; c3v = 0.f; }           // step NSTEPS is pad

    // regs/dts stores (4B lanes at 16B stride: fully-written lines)
    out[NSTEPS + n0 + 0] = fmaf(-sig0, sig0, tkth2);
    out[NSTEPS + n0 + 1] = fmaf(-sig1, sig1, tkth2);
    out[NSTEPS + n0 + 2] = fmaf(-sig2, sig2, tkth2);
    out[2L * NSTEPS + n0 + 0] = d0;
    out[2L * NSTEPS + n0 + 1] = d1;
    out[2L * NSTEPS + n0 + 2] = d2;
    if (n0 + 4 <= NSTEPS) {
        out[NSTEPS + n0 + 3] = fmaf(-sig3, sig3, tkth2);
        out[2L * NSTEPS + n0 + 3] = d3;
    }

    const float4 q0 = make_float4(d0, c0v, d1, c1v);
    const float4 q1 = make_float4(d2, c2v, d3, c3v);

    // ---- tail: identical math to validated fused_pass ----
    float s = th + (r0v - th) * __expf(-k * (tfirst - t0g));   // closed-form ODE seed
    float r = s, P = 1.f;
    GSTEP(q0.x, q0.y)
    GSTEP(q0.z, q0.w)
    GSTEP(q1.x, q1.y)
    GSTEP(q1.z, q1.w)
    float A = P, Bv = fmaf(-P, s, r);

    float iA = A, iB = Bv;
    wave_scan_affine(iA, iB, lane);
    if (lane == 63) { wAs[wid] = iA; wBs[wid] = iB; }
    __syncthreads();
    if (wid == 0) {
        float aA = (lane < 16) ? wAs[lane] : 1.f;
        float aB = (lane < 16) ? wBs[lane] : 0.f;
        wave_scan_affine(aA, aB, lane);
        if (lane < 16) { wAs[lane] = aA; wBs[lane] = aB; }
    }
    __syncthreads();
    float weA = 1.f, weB = 0.f;
    if (wid > 0) { weA = wAs[wid - 1]; weB = wBs[wid - 1]; }
    float eA = __shfl_up(iA, 1, 64), eB = __shfl_up(iB, 1, 64);
    if (lane == 0) { eA = 1.f; eB = 0.f; }
    float Ate = eA * weA;                 // thread-exclusive prefix within block
    float Bte = fmaf(eA, weB, eB);

    // publish block aggregate + device-scope spin barrier
    if (tid == 0) {
        __hip_atomic_store(&gA[bid], wAs[15], __ATOMIC_RELAXED, __HIP_MEMORY_SCOPE_AGENT);
        __hip_atomic_store(&gB[bid], wBs[15], __ATOMIC_RELAXED, __HIP_MEMORY_SCOPE_AGENT);
        __hip_atomic_fetch_add(cnt, 1u, __ATOMIC_ACQ_REL, __HIP_MEMORY_SCOPE_AGENT);
        while (__hip_atomic_load(cnt, __ATOMIC_ACQUIRE, __HIP_MEMORY_SCOPE_AGENT) < NB)
            __builtin_amdgcn_s_sleep(1);
    }
    __syncthreads();

    // shuffle-based scan of the 256 block aggregates (waves 0..3, few barriers)
    float bAv = 1.f, bBv = 0.f;
    if (tid < NB) {
        bAv = __hip_atomic_load(&gA[tid], __ATOMIC_RELAXED, __HIP_MEMORY_SCOPE_AGENT);
        bBv = __hip_atomic_load(&gB[tid], __ATOMIC_RELAXED, __HIP_MEMORY_SCOPE_AGENT);
    }
    if (wid < NB / 64) {
        wave_scan_affine(bAv, bBv, lane);            // inclusive within wave
        if (lane == 63) { wAs[wid] = bAv; wBs[wid] = bBv; }
    }
    __syncthreads();
    if (tid < NB) {
        float Pa = 1.f, Pb = 0.f;                    // prefix of earlier waves
        for (int w = 0; w < wid; ++w) { Pb = fmaf(wAs[w], Pb, wBs[w]); Pa *= wAs[w]; }
        sgA[tid] = bAv * Pa;                         // full inclusive for block tid
        sgB[tid] = fmaf(bAv, Pb, bBv);
    }
    __syncthreads();
    float beA = 1.f, beB = 0.f;
    if (bid > 0) { beA = sgA[bid - 1]; beB = sgB[bid - 1]; }

    // corrected start for this thread's 4 steps, replay, store
    float FA = Ate * beA;
    float FB = fmaf(Ate, beB, Bte);
    float rr = fmaf(FA, r0v, FB);
    float4 ov;
    FSTEP(q0.x, q0.y) ov.x = rr;
    FSTEP(q0.z, q0.w) ov.y = rr;
    FSTEP(q1.x, q1.y) ov.z = rr;
    FSTEP(q1.z, q1.w) ov.w = rr;
    long nb = 4 * c;
    if (nb + 4 <= NSTEPS) {
        *(float4*)(out + nb) = ov;
    } else {                        // last thread only (step NSTEPS is pad)
        out[nb + 0] = ov.x;
        out[nb + 1] = ov.y;
        out[nb + 2] = ov.z;
    }
}

extern "C" void kernel_launch(void* const* d_in, const int* in_sizes, int n_in,
                              void* d_out, int out_size, void* d_ws, size_t ws_size,
                              hipStream_t stream)
{
    const float* trace = (const float*)d_in[0];
    const float* sW    = (const float*)d_in[1];
    const float* sb    = (const float*)d_in[2];
    const float* eW    = (const float*)d_in[3];
    const float* kp    = (const float*)d_in[4];
    const float* thp   = (const float*)d_in[5];
    float* out = (float*)d_out;

    float*        gA  = (float*)d_ws;
    float*        gB  = gA + NB;
    unsigned int* cnt = (unsigned int*)(gB + NB);

    hipMemsetAsync(cnt, 0, sizeof(unsigned int), stream);   // graph-capture-legal memset
    cir_fused<<<NB, NT, 0, stream>>>(trace, sW, sb, eW, kp, thp, out, gA, gB, cnt);
}

// Round 4
// 124.227 us; speedup vs baseline: 1.3482x; 1.2193x over previous
//
#include <hip/hip_runtime.h>
#include <math.h>

// CIRNet, barrier-free 2-kernel split: T=1048576 rows x 18 feats -> r_predicts/regs/dts.
// Evidence: fused 256-block single-kernel variants (R1/R2/R3) all ~50-75us; R0 split
// ~35us. This keeps the split and removes BOTH pathologies:
//  - K1 reads trace via per-wave LDS-transpose staging (coalesced global_load_lds,
//    wave-local s_waitcnt only) instead of 72B-stride float2 (10x L1-txn amplified),
//    AND absorbs the affine-map construction + block scan: writes per-step (d,c),
//    regs/dts, per-thread block-local exclusive prefix, per-block aggregate.
//  - K2 is barrier-free: each block redundantly scans the 1024 block aggregates (8KB,
//    L2-hot), composes its exclusive prefix, replays 4 FSTEPs, stores r_predicts.
// No device-scope spin barrier, no co-residency assumption, no memset.
// All FP math order identical to the validated kernels.
#define NSTEPS   1048575
#define FEAT     18
#define NB1      1024                // K1/K2 blocks
#define NT1      256                 // threads per block (4 waves)
#define NQ       (NB1 * NT1)         // 262144 quads x 4 rows = 1048576 rows
#define SLOTS    608                 // 19 * 32 float4 slots per half-wave pass
#define WBYTES   (SLOTS * 16)        // 9728 B per-wave stage buffer

#define GLDS16(g, l) \
    __builtin_amdgcn_global_load_lds((const __attribute__((address_space(1))) void*)(g), \
                                     (__attribute__((address_space(3))) void*)(l), 16, 0, 0)

#define WAIT_VM0()   asm volatile("s_waitcnt vmcnt(0)" ::: "memory")
#define WAIT_LGKM0() asm volatile("s_waitcnt lgkmcnt(0)" ::: "memory")

// one step + derivative-product update (identical math to validated kernel)
#define GSTEP(dd, cc) { \
    float a   = fmaf(-k, (dd), 1.f); \
    float b   = kth * (dd); \
    float ar  = fabsf(r); \
    float sq  = sqrtf(ar); \
    float inv = (ar > 1e-30f) ? rsqrtf(ar) : 0.f; \
    float g   = fmaf(0.5f * (cc), copysignf(inv, r), a); \
    r = fmaf((cc), sq, fmaf(a, r, b)); \
    P *= g; }

#define FSTEP(dd, cc) { \
    float a = fmaf(-k, (dd), 1.f); \
    float b = kth * (dd); \
    rr = fmaf((cc), sqrtf(fabsf(rr)), fmaf(a, rr, b)); }

// sig & eps dot-products, same fma order as validated kernel
#define DOTSE(S0,S1,S2,S3,S4,S5,S6,S7, E0,E1,E2,E3,E4,E5,E6,E7, sigv, epv) { \
    float sig_ = sb0; \
    sig_ = fmaf((S0), sw0, sig_); sig_ = fmaf((S1), sw1, sig_); \
    sig_ = fmaf((S2), sw2, sig_); sig_ = fmaf((S3), sw3, sig_); \
    sig_ = fmaf((S4), sw4, sig_); sig_ = fmaf((S5), sw5, sig_); \
    sig_ = fmaf((S6), sw6, sig_); sig_ = fmaf((S7), sw7, sig_); \
    float ep_ = 0.f; \
    ep_ = fmaf((E0), ew0, ep_); ep_ = fmaf((E1), ew1, ep_); \
    ep_ = fmaf((E2), ew2, ep_); ep_ = fmaf((E3), ew3, ep_); \
    ep_ = fmaf((E4), ew4, ep_); ep_ = fmaf((E5), ew5, ep_); \
    ep_ = fmaf((E6), ew6, ep_); ep_ = fmaf((E7), ew7, ep_); \
    (sigv) = sig_; (epv) = ep_; }

// read one padded quad (18 float4 at stride-19 slots) and reduce to live scalars
#define EXTRACT_COMPUTE(JROW) { \
    const float4* sr = (const float4*)lw + 19 * (JROW); \
    float4 u0 = sr[0],  u1  = sr[1],  u2  = sr[2],  u3  = sr[3],  u4  = sr[4]; \
    float4 u5 = sr[5],  u6  = sr[6],  u7  = sr[7],  u8  = sr[8]; \
    float4 u9 = sr[9],  u10 = sr[10], u11 = sr[11], u12 = sr[12], u13 = sr[13]; \
    float4 u14 = sr[14], u15 = sr[15], u16 = sr[16], u17 = sr[17]; \
    tfirst = u0.x; t3 = u13.z; \
    d0 = u4.z  - u0.x;  d1 = u9.x - u4.z;  d2 = u13.z - u9.x; \
    float ep0, ep1, ep2; \
    DOTSE(u0.z,u0.w,u1.x,u1.y,u1.z,u1.w,u2.x,u2.y, \
          u2.z,u2.w,u3.x,u3.y,u3.z,u3.w,u4.x,u4.y, sig0, ep0) \
    DOTSE(u5.x,u5.y,u5.z,u5.w,u6.x,u6.y,u6.z,u6.w, \
          u7.x,u7.y,u7.z,u7.w,u8.x,u8.y,u8.z,u8.w, sig1, ep1) \
    DOTSE(u9.z,u9.w,u10.x,u10.y,u10.z,u10.w,u11.x,u11.y, \
          u11.z,u11.w,u12.x,u12.y,u12.z,u12.w,u13.x,u13.y, sig2, ep2) \
    DOTSE(u14.x,u14.y,u14.z,u14.w,u15.x,u15.y,u15.z,u15.w, \
          u16.x,u16.y,u16.z,u16.w,u17.x,u17.y,u17.z,u17.w, sig3, ep3) \
    c0v = sig0 * ep0 * sqrtf(fabsf(d0)); \
    c1v = sig1 * ep1 * sqrtf(fabsf(d1)); \
    c2v = sig2 * ep2 * sqrtf(fabsf(d2)); }

__device__ __forceinline__ void stage_pass(const float4* __restrict__ base4,
                                           char* lds_wave, int lane)
{
    int jr = lane / 19;                 // quad within pass
    int ic = lane - 19 * jr;            // padded col
#pragma unroll
    for (int i = 0; i < 10; ++i) {
        int col = (ic == 18) ? 17 : ic; // pad slot -> duplicate col 17 (in-bounds)
        const float4* src = base4 + (18 * jr + col);
        if (i < 9) {
            GLDS16(src, lds_wave + i * 1024);
        } else if (lane < 32) {         // partial tail: slots 576..607 (exec-masked)
            GLDS16(src, lds_wave + 9 * 1024);
        }
        jr += 3; ic += 7;               // advance slot by 64 = 3*19 + 7
        if (ic >= 19) { ic -= 19; ++jr; }
    }
}

__device__ __forceinline__ void wave_scan_affine(float& A, float& B, int lane) {
#pragma unroll
    for (int d = 1; d < 64; d <<= 1) {
        float pA = __shfl_up(A, d, 64);
        float pB = __shfl_up(B, d, 64);
        if (lane >= d) { B = fmaf(A, pB, B); A *= pA; }
    }
}

// ---------------- K1: stage + coeffs + regs/dts + dc + block scan ----------------
__global__ void __launch_bounds__(NT1) cir_prep(
    const float* __restrict__ trace,
    const float* __restrict__ sW, const float* __restrict__ sb,
    const float* __restrict__ eW, const float* __restrict__ kp,
    const float* __restrict__ thp,
    float* __restrict__ out,
    float2* __restrict__ dc, float2* __restrict__ pref, float2* __restrict__ agg)
{
    __shared__ __align__(16) char stage[4 * WBYTES];        // 38912 B -> 4 blocks/CU
    __shared__ float wAs[4], wBs[4];

    const int tid = threadIdx.x, lane = tid & 63, wid = tid >> 6, bid = blockIdx.x;
    const long c = (long)bid * NT1 + tid;                   // thread's quad index
    char* lw = stage + wid * WBYTES;                        // per-wave private buffer
    const float4* t4 = (const float4*)trace;
    const long waveQuad = (long)bid * NT1 + (long)wid * 64;

    stage_pass(t4 + waveQuad * 18, lw, lane);               // pass 0: lanes 0..31's quads

    const float k = kp[0], th = thp[0], kth = k * th, tkth2 = 2.f * kth;
    const float sb0 = sb[0];
    const float sw0 = sW[0], sw1 = sW[1], sw2 = sW[2], sw3 = sW[3];
    const float sw4 = sW[4], sw5 = sW[5], sw6 = sW[6], sw7 = sW[7];
    const float ew0 = eW[0], ew1 = eW[1], ew2 = eW[2], ew3 = eW[3];
    const float ew4 = eW[4], ew5 = eW[5], ew6 = eW[6], ew7 = eW[7];
    const float t0g = trace[0], r0v = trace[1];

    float tfirst, t3, d0, d1, d2, c0v, c1v, c2v, sig0, sig1, sig2, sig3, ep3;

    WAIT_VM0();                         // pass-0 data in LDS (wave-local wait)
    if (lane < 32) EXTRACT_COMPUTE(lane)
    WAIT_LGKM0();                       // extraction reads done before overwrite

    stage_pass(t4 + (waveQuad + 32) * 18, lw, lane);        // pass 1: lanes 32..63
    WAIT_VM0();
    if (lane >= 32) EXTRACT_COMPUTE(lane - 32)

    // t of next quad's first row: cross-half shuffle; lane 63 loads (1 txn/wave)
    float tnext = __shfl_down(tfirst, 1, 64);
    if (lane == 63)
        tnext = (c + 1 < (long)NQ) ? trace[(c * 4 + 4) * FEAT] : 0.f;
    float d3 = tnext - t3;
    const long n0 = c * 4;
    float c3v = sig3 * ep3 * sqrtf(fabsf(d3));
    if (n0 + 4 > NSTEPS) { d3 = 0.f; c3v = 0.f; }           // step NSTEPS is pad

    // regs/dts stores
    out[NSTEPS + n0 + 0] = fmaf(-sig0, sig0, tkth2);
    out[NSTEPS + n0 + 1] = fmaf(-sig1, sig1, tkth2);
    out[NSTEPS + n0 + 2] = fmaf(-sig2, sig2, tkth2);
    out[2L * NSTEPS + n0 + 0] = d0;
    out[2L * NSTEPS + n0 + 1] = d1;
    out[2L * NSTEPS + n0 + 2] = d2;
    if (n0 + 4 <= NSTEPS) {
        out[NSTEPS + n0 + 3] = fmaf(-sig3, sig3, tkth2);
        out[2L * NSTEPS + n0 + 3] = d3;
    }

    // per-step coefficients for K2's replay
    float4* dc4 = (float4*)dc;
    dc4[2 * c]     = make_float4(d0, c0v, d1, c1v);
    dc4[2 * c + 1] = make_float4(d2, c2v, d3, c3v);

    // affine map for this quad: r -> A*r + B (seed + 4 Newton-linearized steps)
    float s = th + (r0v - th) * __expf(-k * (tfirst - t0g));
    float r = s, P = 1.f;
    GSTEP(d0, c0v)
    GSTEP(d1, c1v)
    GSTEP(d2, c2v)
    GSTEP(d3, c3v)
    float A = P, Bv = fmaf(-P, s, r);

    // block scan over 256 thread maps (4 waves)
    float iA = A, iB = Bv;
    wave_scan_affine(iA, iB, lane);
    if (lane == 63) { wAs[wid] = iA; wBs[wid] = iB; }
    __syncthreads();
    if (wid == 0) {
        float aA = (lane < 4) ? wAs[lane] : 1.f;
        float aB = (lane < 4) ? wBs[lane] : 0.f;
        wave_scan_affine(aA, aB, lane);
        if (lane < 4) { wAs[lane] = aA; wBs[lane] = aB; }
    }
    __syncthreads();
    float weA = 1.f, weB = 0.f;
    if (wid > 0) { weA = wAs[wid - 1]; weB = wBs[wid - 1]; }
    float eA = __shfl_up(iA, 1, 64), eB = __shfl_up(iB, 1, 64);
    if (lane == 0) { eA = 1.f; eB = 0.f; }

    pref[c] = make_float2(eA * weA, fmaf(eA, weB, eB));     // thread-exclusive prefix
    if (tid == 0) agg[bid] = make_float2(wAs[3], wBs[3]);   // block aggregate
}

// ---------------- K2: barrier-free global scan + replay ----------------
__global__ void __launch_bounds__(NT1) cir_final(
    const float* __restrict__ trace,
    const float* __restrict__ kp, const float* __restrict__ thp,
    const float2* __restrict__ dc, const float2* __restrict__ pref,
    const float2* __restrict__ agg,
    float* __restrict__ out)
{
    __shared__ float2 incs[NB1];        // 8 KB inclusive scan of block aggregates
    __shared__ float wA2[4], wB2[4];

    const int tid = threadIdx.x, lane = tid & 63, wid = tid >> 6, bid = blockIdx.x;
    const long c = (long)bid * NT1 + tid;
    const float k = kp[0], th = thp[0], kth = k * th;
    const float r0v = trace[1];

    // every block scans all 1024 aggregates (ordered): 4 sequential per thread
    float2 a0 = agg[4 * tid + 0], a1 = agg[4 * tid + 1];
    float2 a2 = agg[4 * tid + 2], a3 = agg[4 * tid + 3];
    float cA = a0.x, cB = a0.y;                       // compose in order (earlier first)
    cB = fmaf(a1.x, cB, a1.y); cA *= a1.x;
    cB = fmaf(a2.x, cB, a2.y); cA *= a2.x;
    cB = fmaf(a3.x, cB, a3.y); cA *= a3.x;

    float iA = cA, iB = cB;                           // inclusive over thread-chunks
    wave_scan_affine(iA, iB, lane);
    if (lane == 63) { wA2[wid] = iA; wB2[wid] = iB; }
    __syncthreads();
    if (wid == 0) {
        float aA = (lane < 4) ? wA2[lane] : 1.f;
        float aB = (lane < 4) ? wB2[lane] : 0.f;
        wave_scan_affine(aA, aB, lane);
        if (lane < 4) { wA2[lane] = aA; wB2[lane] = aB; }
    }
    __syncthreads();
    float weA = 1.f, weB = 0.f;
    if (wid > 0) { weA = wA2[wid - 1]; weB = wB2[wid - 1]; }
    float eA = __shfl_up(iA, 1, 64), eB = __shfl_up(iB, 1, 64);
    if (lane == 0) { eA = 1.f; eB = 0.f; }
    float EA = eA * weA, EB = fmaf(eA, weB, eB);      // exclusive prefix of chunk 4*tid

    // inclusive values for this thread's 4 aggregates -> LDS
    float xA = a0.x * EA,  xB = fmaf(a0.x, EB, a0.y);
    incs[4 * tid + 0] = make_float2(xA, xB);
    xB = fmaf(a1.x, xB, a1.y); xA *= a1.x;
    incs[4 * tid + 1] = make_float2(xA, xB);
    xB = fmaf(a2.x, xB, a2.y); xA *= a2.x;
    incs[4 * tid + 2] = make_float2(xA, xB);
    xB = fmaf(a3.x, xB, a3.y); xA *= a3.x;
    incs[4 * tid + 3] = make_float2(xA, xB);
    __syncthreads();

    float beA = 1.f, beB = 0.f;
    if (bid > 0) { float2 p = incs[bid - 1]; beA = p.x; beB = p.y; }

    // replay this thread's 4 steps from the corrected start
    const float4* dc4 = (const float4*)dc;
    float4 q0 = dc4[2 * c], q1 = dc4[2 * c + 1];
    float2 pr = pref[c];
    float FA = pr.x * beA;
    float FB = fmaf(pr.x, beB, pr.y);
    float rr = fmaf(FA, r0v, FB);
    float4 ov;
    FSTEP(q0.x, q0.y) ov.x = rr;
    FSTEP(q0.z, q0.w) ov.y = rr;
    FSTEP(q1.x, q1.y) ov.z = rr;
    FSTEP(q1.z, q1.w) ov.w = rr;
    long nb = 4 * c;
    if (nb + 4 <= NSTEPS) {
        *(float4*)(out + nb) = ov;
    } else {                        // last thread only (step NSTEPS is pad)
        out[nb + 0] = ov.x;
        out[nb + 1] = ov.y;
        out[nb + 2] = ov.z;
    }
}

extern "C" void kernel_launch(void* const* d_in, const int* in_sizes, int n_in,
                              void* d_out, int out_size, void* d_ws, size_t ws_size,
                              hipStream_t stream)
{
    const float* trace = (const float*)d_in[0];
    const float* sW    = (const float*)d_in[1];
    const float* sb    = (const float*)d_in[2];
    const float* eW    = (const float*)d_in[3];
    const float* kp    = (const float*)d_in[4];
    const float* thp   = (const float*)d_in[5];
    float* out = (float*)d_out;

    float2* dc   = (float2*)d_ws;           // 4*NQ float2 = 8 MB
    float2* pref = dc + 4L * NQ;            // NQ float2 = 2 MB
    float2* agg  = pref + NQ;               // NB1 float2 = 8 KB

    cir_prep<<<NB1, NT1, 0, stream>>>(trace, sW, sb, eW, kp, thp, out, dc, pref, agg);
    cir_final<<<NB1, NT1, 0, stream>>>(trace, kp, thp, dc, pref, agg, out);
}